// Round 18
// baseline (68.704 us; speedup 1.0000x reference)
//
#include <hip/hip_runtime.h>

#define BB    2048
#define TT    1024
#define TAILN 8
#define NELEM (BB * TT * TAILN)
#define ROWE  (TT * TAILN)            // 8192 elements per b-row
#define NSTEP 32                      // 32-t blocks per wave: exact, no warm-up

typedef float f32x4 __attribute__((ext_vector_type(4)));

// System-scope non-temporal store: sc1 raises coherence scope, nt requests
// no-allocate in L2/LLC.  Goal: stop the 128MB/replay output stream from
// evicting the 208MB input set out of the 256MB Infinity Cache (R17 steady
// state: 133MB of reads still miss LLC every replay).
// Correctness of this exact asm: proven in R15 (passed, exact WRITE_SIZE).
__device__ __forceinline__ void nt_store4(float* p, f32x4 x) {
    asm volatile("global_store_dwordx4 %0, %1, off sc1 nt"
                 :: "v"(p), "v"(x) : "memory");
}

// ---------------------------------------------------------------------------
// EXACT single-pass wave-parallel GAE (R17 structure; only the store encoding
// changed builtin-nt -> sc1 nt).
//  * wave = one b-row; lane l holds the float4 of tails (l&1)*4..+3 at
//    t = t0+(l>>1): every load/store is one fully-contiguous 1KB transaction.
//  * suffix scan of affine maps (A,B) via 5-step shfl butterfly; carry
//    crosses 32-t blocks via lane-{0,1} broadcast; 32 steps tile [0,1024).
//  * simple load->compute->store loop, unroll 4 (R17-proven; no named
//    rotation -- R16's corruption combo is avoided).
//  * fused per-block dtype detect (R15/R17): 2048 words (8KB) at the block's
//    own rows.  Bool evidence (word>1) ~60 expected hits; missed float
//    detection harmless (int32-nd == float-nd for exact 0/1 data).
// ---------------------------------------------------------------------------
template <int MODE>
__device__ __forceinline__ void gae_wave(
    const float* __restrict__ r, const void* __restrict__ term,
    const float* __restrict__ v, const float* __restrict__ nv,
    float* __restrict__ adv, float* __restrict__ ret,
    int b, int lane)
{
    const unsigned eb = (unsigned)b * (unsigned)ROWE;
    const int th = lane & 1;                   // tail half
    const int tq = lane >> 1;                  // t within 32-t block

    float cx = 0.0f, cy = 0.0f, cz = 0.0f, cw = 0.0f;   // carry (4 tails)

    #pragma unroll 4
    for (int k = 0; k < NSTEP; ++k) {
        const int t0 = TT - 32 * (k + 1);                // 992, 960, ..., 0
        const unsigned i = eb + (unsigned)t0 * 8u + ((unsigned)lane << 2);

        const float4 R4 = *(const float4*)(r  + i);
        const float4 V4 = *(const float4*)(v  + i);
        const float4 N4 = *(const float4*)(nv + i);

        float n0, n1, n2, n3;
        if (MODE == 1) {
            const unsigned tw =
                ((const unsigned*)term)[((eb + (unsigned)t0 * 8u) >> 2) + (unsigned)lane];
            n0 = ( tw        & 0xFFu) ? 0.0f : 1.0f;
            n1 = ((tw >>  8) & 0xFFu) ? 0.0f : 1.0f;
            n2 = ((tw >> 16) & 0xFFu) ? 0.0f : 1.0f;
            n3 = ((tw >> 24) & 0xFFu) ? 0.0f : 1.0f;
        } else if (MODE == 2) {
            const uint4 T4 = *(const uint4*)((const unsigned*)term + i);
            n0 = 1.0f - __uint_as_float(T4.x);
            n1 = 1.0f - __uint_as_float(T4.y);
            n2 = 1.0f - __uint_as_float(T4.z);
            n3 = 1.0f - __uint_as_float(T4.w);
        } else {
            const uint4 T4 = *(const uint4*)((const unsigned*)term + i);
            n0 = T4.x ? 0.0f : 1.0f;  n1 = T4.y ? 0.0f : 1.0f;
            n2 = T4.z ? 0.0f : 1.0f;  n3 = T4.w ? 0.0f : 1.0f;
        }

        // per-t affine maps: gae_t = B + A * gae_{t+1}
        float A0 = 0.9405f * n0, B0 = fmaf(0.99f * n0, N4.x, R4.x) - V4.x;
        float A1 = 0.9405f * n1, B1 = fmaf(0.99f * n1, N4.y, R4.y) - V4.y;
        float A2 = 0.9405f * n2, B2 = fmaf(0.99f * n2, N4.z, R4.z) - V4.z;
        float A3 = 0.9405f * n3, B3 = fmaf(0.99f * n3, N4.w, R4.w) - V4.w;

        #pragma unroll
        for (int s = 1; s < 32; s <<= 1) {     // inclusive suffix over t's
            const int  src   = lane + 2 * s;
            const bool valid = (tq + s) < 32;
            float a, bb;
            a = __shfl(A0, src); bb = __shfl(B0, src);
            B0 = fmaf(A0, valid ? bb : 0.0f, B0); A0 *= valid ? a : 1.0f;
            a = __shfl(A1, src); bb = __shfl(B1, src);
            B1 = fmaf(A1, valid ? bb : 0.0f, B1); A1 *= valid ? a : 1.0f;
            a = __shfl(A2, src); bb = __shfl(B2, src);
            B2 = fmaf(A2, valid ? bb : 0.0f, B2); A2 *= valid ? a : 1.0f;
            a = __shfl(A3, src); bb = __shfl(B3, src);
            B3 = fmaf(A3, valid ? bb : 0.0f, B3); A3 *= valid ? a : 1.0f;
        }

        const float g0 = fmaf(A0, cx, B0);
        const float g1 = fmaf(A1, cy, B1);
        const float g2 = fmaf(A2, cz, B2);
        const float g3 = fmaf(A3, cw, B3);

        f32x4 g4; g4[0] = g0;        g4[1] = g1;        g4[2] = g2;        g4[3] = g3;
        f32x4 rr; rr[0] = g0 + V4.x; rr[1] = g1 + V4.y; rr[2] = g2 + V4.z; rr[3] = g3 + V4.w;
        nt_store4(adv + i, g4);
        nt_store4(ret + i, rr);

        // next block's carry = gae at this block's lowest t (lanes 0/1)
        cx = __shfl(g0, th); cy = __shfl(g1, th);
        cz = __shfl(g2, th); cw = __shfl(g3, th);
    }
}

__global__ __launch_bounds__(256)
void gae_kernel(const float* __restrict__ r, const void* __restrict__ term,
                const float* __restrict__ v, const float* __restrict__ nv,
                float* __restrict__ adv, float* __restrict__ ret)
{
    // ---- per-block terminated-dtype detection (2048 words = 8KB) ----
    __shared__ int sflag;
    if (threadIdx.x == 0) sflag = 0;
    __syncthreads();
    {
        const unsigned w0 = (unsigned)blockIdx.x * 8192u;  // own rows in bool mode
        int ev = 0;
        #pragma unroll
        for (int j = 0; j < 8; ++j) {
            const unsigned w = ((const unsigned*)term)[w0 + threadIdx.x + 256u * j];
            if (w == 0x3F800000u) ev |= 2;     // float 1.0f
            else if (w > 1u)      ev |= 1;     // packed bool bytes
        }
        if (ev) atomicOr(&sflag, ev);
    }
    __syncthreads();
    const int f = sflag;

    const int w    = threadIdx.x >> 6;        // 4 waves = 4 b-rows per block
    const int lane = threadIdx.x & 63;
    const int b    = blockIdx.x * 4 + w;
    if (f & 1)      gae_wave<1>(r, term, v, nv, adv, ret, b, lane);
    else if (f & 2) gae_wave<2>(r, term, v, nv, adv, ret, b, lane);
    else            gae_wave<0>(r, term, v, nv, adv, ret, b, lane);
}

extern "C" void kernel_launch(void* const* d_in, const int* in_sizes, int n_in,
                              void* d_out, int out_size, void* d_ws, size_t ws_size,
                              hipStream_t stream) {
    const float* reward = (const float*)d_in[0];
    const void*  term   = d_in[1];
    const float* value  = (const float*)d_in[2];
    const float* nextv  = (const float*)d_in[3];
    float* adv  = (float*)d_out;
    float* ret  = adv + NELEM;

    // single launch: 512 blocks x 256 thr = 2048 waves = 8/CU; exact scan
    hipLaunchKernelGGL(gae_kernel, dim3(BB / 4), dim3(256), 0, stream,
                       reward, term, value, nextv, adv, ret);
}

// Round 19
// 67.191 us; speedup vs baseline: 1.0225x; 1.0225x over previous
//
#include <hip/hip_runtime.h>

#define BB    2048
#define TT    1024
#define TAILN 8
#define NELEM (BB * TT * TAILN)
#define ROWE  (TT * TAILN)            // 8192 elements per b-row
#define NSTEP 32                      // 32-t blocks per wave: exact, no warm-up

typedef float f32x4 __attribute__((ext_vector_type(4)));

// ---------------------------------------------------------------------------
// EXACT single-pass wave-parallel GAE — final configuration (== R17, best
// measured 66.9us; R18's sc1-nt store was a null on FETCH and ~2% slower).
//  * wave = one b-row; lane l holds the float4 of tails (l&1)*4..+3 at
//    t = t0+(l>>1): every load/store is one fully-contiguous 1KB transaction.
//  * backward recurrence = suffix scan of affine maps (A,B) via 5-step shfl
//    butterfly; carry crosses 32-t blocks via lane-{0,1} broadcast.
//    32 steps tile [0,1024) exactly -- read factor 1.0, no warm-up.
//  * simple load->compute->store loop, unroll 4; no named-buffer rotation,
//    no inline-asm stores (R16's corruption combo excluded).
//  * stores: __builtin_nontemporal_store on dense full lines (exact
//    131072KB WRITE_SIZE across rounds).
//  * fused per-block dtype detect: 2048 term words (8KB) at the block's own
//    rows.  Bool evidence (word>1): ~60 expected hits at 1% density.  A
//    missed float detection is harmless (int32-nd == float-nd for 0/1 data).
// Ceiling accounting (R1-R18): actual HBM traffic 264MB/replay at ~3.95TB/s
// effective; rate invariant to occupancy/pipeline/store-type; all remaining
// gains were byte cuts, now at the exact-traffic floor.
// ---------------------------------------------------------------------------
template <int MODE>
__device__ __forceinline__ void gae_wave(
    const float* __restrict__ r, const void* __restrict__ term,
    const float* __restrict__ v, const float* __restrict__ nv,
    float* __restrict__ adv, float* __restrict__ ret,
    int b, int lane)
{
    const unsigned eb = (unsigned)b * (unsigned)ROWE;
    const int th = lane & 1;                   // tail half
    const int tq = lane >> 1;                  // t within 32-t block

    float cx = 0.0f, cy = 0.0f, cz = 0.0f, cw = 0.0f;   // carry (4 tails)

    #pragma unroll 4
    for (int k = 0; k < NSTEP; ++k) {
        const int t0 = TT - 32 * (k + 1);                // 992, 960, ..., 0
        const unsigned i = eb + (unsigned)t0 * 8u + ((unsigned)lane << 2);

        const float4 R4 = *(const float4*)(r  + i);
        const float4 V4 = *(const float4*)(v  + i);
        const float4 N4 = *(const float4*)(nv + i);

        float n0, n1, n2, n3;
        if (MODE == 1) {
            const unsigned tw =
                ((const unsigned*)term)[((eb + (unsigned)t0 * 8u) >> 2) + (unsigned)lane];
            n0 = ( tw        & 0xFFu) ? 0.0f : 1.0f;
            n1 = ((tw >>  8) & 0xFFu) ? 0.0f : 1.0f;
            n2 = ((tw >> 16) & 0xFFu) ? 0.0f : 1.0f;
            n3 = ((tw >> 24) & 0xFFu) ? 0.0f : 1.0f;
        } else if (MODE == 2) {
            const uint4 T4 = *(const uint4*)((const unsigned*)term + i);
            n0 = 1.0f - __uint_as_float(T4.x);
            n1 = 1.0f - __uint_as_float(T4.y);
            n2 = 1.0f - __uint_as_float(T4.z);
            n3 = 1.0f - __uint_as_float(T4.w);
        } else {
            const uint4 T4 = *(const uint4*)((const unsigned*)term + i);
            n0 = T4.x ? 0.0f : 1.0f;  n1 = T4.y ? 0.0f : 1.0f;
            n2 = T4.z ? 0.0f : 1.0f;  n3 = T4.w ? 0.0f : 1.0f;
        }

        // per-t affine maps: gae_t = B + A * gae_{t+1}
        float A0 = 0.9405f * n0, B0 = fmaf(0.99f * n0, N4.x, R4.x) - V4.x;
        float A1 = 0.9405f * n1, B1 = fmaf(0.99f * n1, N4.y, R4.y) - V4.y;
        float A2 = 0.9405f * n2, B2 = fmaf(0.99f * n2, N4.z, R4.z) - V4.z;
        float A3 = 0.9405f * n3, B3 = fmaf(0.99f * n3, N4.w, R4.w) - V4.w;

        #pragma unroll
        for (int s = 1; s < 32; s <<= 1) {     // inclusive suffix over t's
            const int  src   = lane + 2 * s;
            const bool valid = (tq + s) < 32;
            float a, bb;
            a = __shfl(A0, src); bb = __shfl(B0, src);
            B0 = fmaf(A0, valid ? bb : 0.0f, B0); A0 *= valid ? a : 1.0f;
            a = __shfl(A1, src); bb = __shfl(B1, src);
            B1 = fmaf(A1, valid ? bb : 0.0f, B1); A1 *= valid ? a : 1.0f;
            a = __shfl(A2, src); bb = __shfl(B2, src);
            B2 = fmaf(A2, valid ? bb : 0.0f, B2); A2 *= valid ? a : 1.0f;
            a = __shfl(A3, src); bb = __shfl(B3, src);
            B3 = fmaf(A3, valid ? bb : 0.0f, B3); A3 *= valid ? a : 1.0f;
        }

        const float g0 = fmaf(A0, cx, B0);
        const float g1 = fmaf(A1, cy, B1);
        const float g2 = fmaf(A2, cz, B2);
        const float g3 = fmaf(A3, cw, B3);

        f32x4 g4; g4[0] = g0;        g4[1] = g1;        g4[2] = g2;        g4[3] = g3;
        f32x4 rr; rr[0] = g0 + V4.x; rr[1] = g1 + V4.y; rr[2] = g2 + V4.z; rr[3] = g3 + V4.w;
        __builtin_nontemporal_store(g4, (f32x4*)(adv + i));
        __builtin_nontemporal_store(rr, (f32x4*)(ret + i));

        // next block's carry = gae at this block's lowest t (lanes 0/1)
        cx = __shfl(g0, th); cy = __shfl(g1, th);
        cz = __shfl(g2, th); cw = __shfl(g3, th);
    }
}

__global__ __launch_bounds__(256)
void gae_kernel(const float* __restrict__ r, const void* __restrict__ term,
                const float* __restrict__ v, const float* __restrict__ nv,
                float* __restrict__ adv, float* __restrict__ ret)
{
    // ---- per-block terminated-dtype detection (2048 words = 8KB) ----
    __shared__ int sflag;
    if (threadIdx.x == 0) sflag = 0;
    __syncthreads();
    {
        const unsigned w0 = (unsigned)blockIdx.x * 8192u;  // own rows in bool mode
        int ev = 0;
        #pragma unroll
        for (int j = 0; j < 8; ++j) {
            const unsigned w = ((const unsigned*)term)[w0 + threadIdx.x + 256u * j];
            if (w == 0x3F800000u) ev |= 2;     // float 1.0f
            else if (w > 1u)      ev |= 1;     // packed bool bytes
        }
        if (ev) atomicOr(&sflag, ev);
    }
    __syncthreads();
    const int f = sflag;

    const int w    = threadIdx.x >> 6;        // 4 waves = 4 b-rows per block
    const int lane = threadIdx.x & 63;
    const int b    = blockIdx.x * 4 + w;
    if (f & 1)      gae_wave<1>(r, term, v, nv, adv, ret, b, lane);
    else if (f & 2) gae_wave<2>(r, term, v, nv, adv, ret, b, lane);
    else            gae_wave<0>(r, term, v, nv, adv, ret, b, lane);
}

extern "C" void kernel_launch(void* const* d_in, const int* in_sizes, int n_in,
                              void* d_out, int out_size, void* d_ws, size_t ws_size,
                              hipStream_t stream) {
    const float* reward = (const float*)d_in[0];
    const void*  term   = d_in[1];
    const float* value  = (const float*)d_in[2];
    const float* nextv  = (const float*)d_in[3];
    float* adv  = (float*)d_out;
    float* ret  = adv + NELEM;

    // single launch: 512 blocks x 256 thr = 2048 waves = 8/CU; exact scan
    hipLaunchKernelGGL(gae_kernel, dim3(BB / 4), dim3(256), 0, stream,
                       reward, term, value, nextv, adv, ret);
}